// Round 8
// baseline (339.835 us; speedup 1.0000x reference)
//
#include <hip/hip_runtime.h>
#include <stdint.h>

#define ROWLEN 16384
#define NT 512
#define VPT 8   // uint4 per thread: 512 threads * 4 elems * 8 = 16384
#define NBLK 768 // persistent blocks: 3 per CU * 256 CUs

typedef uint32_t uint32x4 __attribute__((ext_vector_type(4)));

// Barrier that does NOT drain vmcnt: all barriers in this kernel protect LDS
// only (row data lives in registers). Prefetched next-row global loads stay
// in flight across the whole selection phase — this is what makes the
// persistent-block double-buffer pipeline overlap loads with selection.
#define SYNC_LDS() do { \
    asm volatile("s_waitcnt lgkmcnt(0)" ::: "memory"); \
    __builtin_amdgcn_s_barrier(); \
} while (0)

// Parallel suffix-scan bin select: finds largest bin b with suffix_count(b) >= kk.
template <int NB>
__device__ __forceinline__ void select_bin(const uint32_t* __restrict__ hist,
                                           uint32_t* __restrict__ s_part,
                                           uint32_t* s_bin, int* s_kk, int* s_ceq,
                                           int kk, int tid)
{
    constexpr int C = NB / NT;   // bins per thread (4 for 2048, 2 for 1024)
    uint32_t s = 0;
    #pragma unroll
    for (int j = 0; j < C; ++j) s += hist[tid * C + j];
    s_part[tid] = s;
    SYNC_LDS();
    if (tid < 64) {              // wave 0: 64 groups of 8 thread-chunks
        uint32_t g = 0;
        #pragma unroll
        for (int j = 0; j < 8; ++j) g += s_part[tid * 8 + j];
        uint32_t S = g;          // suffix-inclusive scan (descending bins = ascending idx)
        #pragma unroll
        for (int off = 1; off < 64; off <<= 1) {
            uint32_t o = __shfl_down(S, off, 64);
            if (tid + off < 64) S += o;
        }
        unsigned long long m = __ballot(S >= (uint32_t)kk);
        int c = 63 - __builtin_clzll(m);                 // crossing group
        uint32_t hv = __shfl(S, (c + 1) & 63, 64);
        uint32_t higher = (c == 63) ? 0u : hv;           // count in groups above c
        if (tid == 0) {
            uint32_t pp[8];
            #pragma unroll
            for (int j = 0; j < 8; ++j) pp[j] = s_part[c * 8 + j];
            int kk2 = kk - (int)higher;
            int cum = 0, j = 7;
            #pragma unroll
            for (int it = 7; it > 0; --it) {
                int cc = (int)pp[j];
                if (cum + cc >= kk2) break;
                cum += cc; --j;
            }
            int tt = c * 8 + j;
            int kk3 = kk2 - cum;
            uint32_t bb[C];
            #pragma unroll
            for (int jj = 0; jj < C; ++jj) bb[jj] = hist[tt * C + jj];
            int cum2 = 0, b = C - 1;
            #pragma unroll
            for (int it = C - 1; it > 0; --it) {
                int cc = (int)bb[b];
                if (cum2 + cc >= kk3) break;
                cum2 += cc; --b;
            }
            *s_bin = (uint32_t)(tt * C + b);
            *s_kk  = kk3 - cum2;
            *s_ceq = (int)bb[b];
        }
    }
    SYNC_LDS();
}

struct Shared {
    uint32_t hist[2048];   // [0..1023]: round-1/2 bins + tie idx; [1024..2047]: candidates + tie flags
    uint32_t s_part[NT];
    uint32_t s_bin;
    int s_kk, s_ceq, s_cnt;
};

// Full per-row selection + filtered write. v[] must already be loaded.
__device__ __forceinline__ void process_row(const uint4 (&v)[VPT], uint32x4* __restrict__ outr,
                                            int k, int tid, Shared& sh)
{
    uint32_t* hist = sh.hist;
    // Barrier: previous row's rare-path phase C may still be reading hist.
    SYNC_LDS();
    hist[tid] = 0; hist[tid + 512] = 0; hist[tid + 1024] = 0; hist[tid + 1536] = 0;
    if (tid == 0) sh.s_cnt = 0;
    SYNC_LDS();

    // round-0 histogram: 11-bit digit (bits 30:20) over abs bit pattern
    #pragma unroll
    for (int i = 0; i < VPT; ++i) {
        atomicAdd(&hist[(v[i].x & 0x7FFFFFFFu) >> 20], 1u);
        atomicAdd(&hist[(v[i].y & 0x7FFFFFFFu) >> 20], 1u);
        atomicAdd(&hist[(v[i].z & 0x7FFFFFFFu) >> 20], 1u);
        atomicAdd(&hist[(v[i].w & 0x7FFFFFFFu) >> 20], 1u);
    }
    SYNC_LDS();
    select_bin<2048>(hist, sh.s_part, &sh.s_bin, &sh.s_kk, &sh.s_ceq, k, tid);
    const uint32_t b0 = sh.s_bin;
    int kk = sh.s_kk;
    const int ceq0 = sh.s_ceq;

    hist[tid] = 0; hist[tid + 512] = 0;
    SYNC_LDS();

    uint32_t T; int e, ceqT;
    if (ceq0 <= 1024) {
        // candidate path: compact survivors, rounds 1-2 over <=1024 elems
        uint32_t* cand = hist + 1024;
        #pragma unroll
        for (int i = 0; i < VPT; ++i) {
            uint32_t a;
            a = v[i].x & 0x7FFFFFFFu; if ((a >> 20) == b0) { cand[atomicAdd(&sh.s_cnt, 1)] = a; atomicAdd(&hist[(a >> 10) & 1023u], 1u); }
            a = v[i].y & 0x7FFFFFFFu; if ((a >> 20) == b0) { cand[atomicAdd(&sh.s_cnt, 1)] = a; atomicAdd(&hist[(a >> 10) & 1023u], 1u); }
            a = v[i].z & 0x7FFFFFFFu; if ((a >> 20) == b0) { cand[atomicAdd(&sh.s_cnt, 1)] = a; atomicAdd(&hist[(a >> 10) & 1023u], 1u); }
            a = v[i].w & 0x7FFFFFFFu; if ((a >> 20) == b0) { cand[atomicAdd(&sh.s_cnt, 1)] = a; atomicAdd(&hist[(a >> 10) & 1023u], 1u); }
        }
        SYNC_LDS();
        select_bin<1024>(hist, sh.s_part, &sh.s_bin, &sh.s_kk, &sh.s_ceq, kk, tid);
        const uint32_t b1 = sh.s_bin;
        kk = sh.s_kk;
        hist[tid] = 0; hist[tid + 512] = 0;
        SYNC_LDS();
        for (int t = tid; t < ceq0; t += NT) {
            uint32_t a = cand[t];
            if (((a >> 10) & 1023u) == b1) atomicAdd(&hist[a & 1023u], 1u);
        }
        SYNC_LDS();
        select_bin<1024>(hist, sh.s_part, &sh.s_bin, &sh.s_kk, &sh.s_ceq, kk, tid);
        T = (b0 << 20) | (b1 << 10) | sh.s_bin;
        e = sh.s_kk; ceqT = sh.s_ceq;
    } else {
        // fallback (pathological skew): full-data rounds from registers
        #pragma unroll
        for (int i = 0; i < VPT; ++i) {
            uint32_t a;
            a = v[i].x & 0x7FFFFFFFu; if ((a >> 20) == b0) atomicAdd(&hist[(a >> 10) & 1023u], 1u);
            a = v[i].y & 0x7FFFFFFFu; if ((a >> 20) == b0) atomicAdd(&hist[(a >> 10) & 1023u], 1u);
            a = v[i].z & 0x7FFFFFFFu; if ((a >> 20) == b0) atomicAdd(&hist[(a >> 10) & 1023u], 1u);
            a = v[i].w & 0x7FFFFFFFu; if ((a >> 20) == b0) atomicAdd(&hist[(a >> 10) & 1023u], 1u);
        }
        SYNC_LDS();
        select_bin<1024>(hist, sh.s_part, &sh.s_bin, &sh.s_kk, &sh.s_ceq, kk, tid);
        const uint32_t b1 = sh.s_bin;
        kk = sh.s_kk;
        hist[tid] = 0; hist[tid + 512] = 0;
        SYNC_LDS();
        const uint32_t pfx = (b0 << 10) | b1;
        #pragma unroll
        for (int i = 0; i < VPT; ++i) {
            uint32_t a;
            a = v[i].x & 0x7FFFFFFFu; if ((a >> 10) == pfx) atomicAdd(&hist[a & 1023u], 1u);
            a = v[i].y & 0x7FFFFFFFu; if ((a >> 10) == pfx) atomicAdd(&hist[a & 1023u], 1u);
            a = v[i].z & 0x7FFFFFFFu; if ((a >> 10) == pfx) atomicAdd(&hist[a & 1023u], 1u);
            a = v[i].w & 0x7FFFFFFFu; if ((a >> 10) == pfx) atomicAdd(&hist[a & 1023u], 1u);
        }
        SYNC_LDS();
        select_bin<1024>(hist, sh.s_part, &sh.s_bin, &sh.s_kk, &sh.s_ceq, kk, tid);
        T = (b0 << 20) | (b1 << 10) | sh.s_bin;
        e = sh.s_kk; ceqT = sh.s_ceq;
    }

    // tie at the cutoff (≈never on random data): lowest-index-first
    const bool rare = (ceqT != e);
    int nc = 0;
    if (rare) {
        if (tid == 0) sh.s_cnt = 0;
        SYNC_LDS();
        #pragma unroll
        for (int i = 0; i < VPT; ++i) {
            uint32_t p4 = (uint32_t)(4 * (i * NT + tid));
            if ((v[i].x & 0x7FFFFFFFu) == T) { int q = atomicAdd(&sh.s_cnt, 1); if (q < 1024) hist[q] = p4 + 0u; }
            if ((v[i].y & 0x7FFFFFFFu) == T) { int q = atomicAdd(&sh.s_cnt, 1); if (q < 1024) hist[q] = p4 + 1u; }
            if ((v[i].z & 0x7FFFFFFFu) == T) { int q = atomicAdd(&sh.s_cnt, 1); if (q < 1024) hist[q] = p4 + 2u; }
            if ((v[i].w & 0x7FFFFFFFu) == T) { int q = atomicAdd(&sh.s_cnt, 1); if (q < 1024) hist[q] = p4 + 3u; }
        }
        SYNC_LDS();
        nc = sh.s_cnt; if (nc > 1024) nc = 1024;
        for (int t = tid; t < nc; t += NT) {
            uint32_t my = hist[t];
            int rank = 0;
            for (int j = 0; j < nc; ++j) rank += (hist[j] < my) ? 1 : 0;
            hist[1024 + t] = (rank < e) ? 1u : 0u;
        }
        SYNC_LDS();
    }

    // phase C: registers -> HBM, nontemporal
    auto filt = [&](uint32_t bits, uint32_t idx) -> uint32_t {
        uint32_t key = bits & 0x7FFFFFFFu;
        if (key > T) return bits;
        if (key < T) return 0u;
        if (!rare) return bits;
        for (int j = 0; j < nc; ++j)
            if (hist[j] == idx) return hist[1024 + j] ? bits : 0u;
        return 0u;
    };
    #pragma unroll
    for (int i = 0; i < VPT; ++i) {
        int p = i * NT + tid;
        uint32_t p4 = (uint32_t)(4 * p);
        uint32x4 o;
        o.x = filt(v[i].x, p4 + 0u);
        o.y = filt(v[i].y, p4 + 1u);
        o.z = filt(v[i].z, p4 + 2u);
        o.w = filt(v[i].w, p4 + 3u);
        __builtin_nontemporal_store(o, &outr[p]);
    }
}

// Persistent blocks (3/CU), row double-buffered: next row's 32 loads are
// issued BEFORE the current row's selection; SYNC_LDS barriers don't drain
// vmcnt, so those loads stay in flight across the whole selection phase.
// VGPR budget: 2 rows = 64 data + ~10 temps, under the (512,6) cap of ~85.
__global__ __launch_bounds__(NT, 6) void topk_abs_kernel(
    const uint32_t* __restrict__ x, const int* __restrict__ kptr,
    uint32_t* __restrict__ out, int rows, int nblk)
{
    __shared__ Shared sh;
    const int tid = threadIdx.x;
    const int k = *kptr;

    uint4 va[VPT], vb[VPT];
    int r = blockIdx.x;
    if (r >= rows) return;

    const uint4* xr = (const uint4*)(x + (size_t)r * ROWLEN);
    #pragma unroll
    for (int i = 0; i < VPT; ++i) va[i] = xr[i * NT + tid];

    for (;;) {
        int rn = r + nblk;
        if (rn < rows) {   // prefetch next row; stays in flight during selection
            const uint4* xn = (const uint4*)(x + (size_t)rn * ROWLEN);
            #pragma unroll
            for (int i = 0; i < VPT; ++i) vb[i] = xn[i * NT + tid];
        }
        process_row(va, (uint32x4*)(out + (size_t)r * ROWLEN), k, tid, sh);
        if (rn >= rows) break;
        #pragma unroll
        for (int i = 0; i < VPT; ++i) va[i] = vb[i];   // regs only; loads long since landed
        r = rn;
    }
}

extern "C" void kernel_launch(void* const* d_in, const int* in_sizes, int n_in,
                              void* d_out, int out_size, void* d_ws, size_t ws_size,
                              hipStream_t stream) {
    const uint32_t* x = (const uint32_t*)d_in[0];
    const int* kptr   = (const int*)d_in[1];
    uint32_t* out     = (uint32_t*)d_out;
    const int rows = in_sizes[0] / ROWLEN;   // 4096 rows of 16384
    const int nblk = rows < NBLK ? rows : NBLK;
    topk_abs_kernel<<<nblk, NT, 0, stream>>>(x, kptr, out, rows, nblk);
}

// Round 9
// 94.598 us; speedup vs baseline: 3.5924x; 3.5924x over previous
//
#include <hip/hip_runtime.h>
#include <stdint.h>

#define ROWLEN 16384
#define NT 512
#define VPT 8   // uint4 per thread: 512 threads * 4 elems * 8 = 16384

typedef uint32_t uint32x4 __attribute__((ext_vector_type(4)));

// Parallel suffix-scan bin select: finds largest bin b with suffix_count(b) >= kk.
// Writes s_bin (bin), s_kk (rank within bin, from top), s_ceq (count in bin).
// All NT threads must call (contains barriers).
template <int NB>
__device__ __forceinline__ void select_bin(const uint32_t* __restrict__ hist,
                                           uint32_t* __restrict__ s_part,
                                           uint32_t* s_bin, int* s_kk, int* s_ceq,
                                           int kk, int tid)
{
    constexpr int C = NB / NT;   // bins per thread (4 for 2048, 2 for 1024)
    uint32_t s = 0;
    #pragma unroll
    for (int j = 0; j < C; ++j) s += hist[tid * C + j];
    s_part[tid] = s;
    __syncthreads();
    if (tid < 64) {              // wave 0: 64 groups of 8 thread-chunks
        uint32_t g = 0;
        #pragma unroll
        for (int j = 0; j < 8; ++j) g += s_part[tid * 8 + j];
        uint32_t S = g;          // suffix-inclusive scan (descending bins = ascending idx)
        #pragma unroll
        for (int off = 1; off < 64; off <<= 1) {
            uint32_t o = __shfl_down(S, off, 64);
            if (tid + off < 64) S += o;
        }
        unsigned long long m = __ballot(S >= (uint32_t)kk);
        int c = 63 - __builtin_clzll(m);                 // crossing group
        uint32_t hv = __shfl(S, (c + 1) & 63, 64);
        uint32_t higher = (c == 63) ? 0u : hv;           // count in groups above c
        if (tid == 0) {
            uint32_t pp[8];
            #pragma unroll
            for (int j = 0; j < 8; ++j) pp[j] = s_part[c * 8 + j];   // independent loads
            int kk2 = kk - (int)higher;
            int cum = 0, j = 7;
            #pragma unroll
            for (int it = 7; it > 0; --it) {
                int cc = (int)pp[j];
                if (cum + cc >= kk2) break;
                cum += cc; --j;
            }
            int tt = c * 8 + j;
            int kk3 = kk2 - cum;
            uint32_t bb[C];
            #pragma unroll
            for (int jj = 0; jj < C; ++jj) bb[jj] = hist[tt * C + jj];
            int cum2 = 0, b = C - 1;
            #pragma unroll
            for (int it = C - 1; it > 0; --it) {
                int cc = (int)bb[b];
                if (cum2 + cc >= kk3) break;
                cum2 += cc; --b;
            }
            *s_bin = (uint32_t)(tt * C + b);
            *s_kk  = kk3 - cum2;
            *s_ceq = (int)bb[b];
        }
    }
    __syncthreads();
}

// __launch_bounds__(512, 6): 3 blocks/CU, 40 VGPR — the proven no-spill
// operating point (R4: 94.8us). (512,8) and any 2-rows-live scheme make the
// allocator spill the row array to scratch (R5: 166us, R8: 340us — FETCH/WRITE
// inflate by the spill round-trip). Register-resident single row is the max.
__global__ __launch_bounds__(NT, 6) void topk_abs_kernel(
    const uint32_t* __restrict__ x, const int* __restrict__ kptr,
    uint32_t* __restrict__ out)
{
    __shared__ uint32_t hist[2048];   // lower 1024: round-1/2 bins, tie idx; upper 1024: candidates, tie flags
    __shared__ uint32_t s_part[NT];
    __shared__ uint32_t s_bin;
    __shared__ int s_kk, s_ceq, s_cnt;

    const int tid = threadIdx.x;
    const uint4* __restrict__ xr  = (const uint4*)(x   + (size_t)blockIdx.x * ROWLEN);
    uint32x4* __restrict__ outr   = (uint32x4*)   (out + (size_t)blockIdx.x * ROWLEN);
    const int k = *kptr;

    // ---- Phase A: HBM -> registers (32 VGPRs), fully coalesced 16 B/lane ----
    uint4 v[VPT];
    #pragma unroll
    for (int i = 0; i < VPT; ++i) v[i] = xr[i * NT + tid];

    // round-0 histogram: 11-bit digit (bits 30:20) over abs bit pattern
    hist[tid] = 0; hist[tid + 512] = 0; hist[tid + 1024] = 0; hist[tid + 1536] = 0;
    __syncthreads();
    #pragma unroll
    for (int i = 0; i < VPT; ++i) {
        atomicAdd(&hist[(v[i].x & 0x7FFFFFFFu) >> 20], 1u);
        atomicAdd(&hist[(v[i].y & 0x7FFFFFFFu) >> 20], 1u);
        atomicAdd(&hist[(v[i].z & 0x7FFFFFFFu) >> 20], 1u);
        atomicAdd(&hist[(v[i].w & 0x7FFFFFFFu) >> 20], 1u);
    }
    __syncthreads();
    select_bin<2048>(hist, s_part, &s_bin, &s_kk, &s_ceq, k, tid);
    const uint32_t b0 = s_bin;
    int kk = s_kk;
    const int ceq0 = s_ceq;

    // clear lower 1024 bins + candidate counter
    hist[tid] = 0; hist[tid + 512] = 0;
    if (tid == 0) s_cnt = 0;
    __syncthreads();

    uint32_t T; int e, ceqT;
    if (ceq0 <= 1024) {
        // ---- candidate path: compact survivors, rounds 1-2 over <=1024 elems ----
        uint32_t* cand = hist + 1024;
        #pragma unroll
        for (int i = 0; i < VPT; ++i) {
            uint32_t a;
            a = v[i].x & 0x7FFFFFFFu; if ((a >> 20) == b0) { cand[atomicAdd(&s_cnt, 1)] = a; atomicAdd(&hist[(a >> 10) & 1023u], 1u); }
            a = v[i].y & 0x7FFFFFFFu; if ((a >> 20) == b0) { cand[atomicAdd(&s_cnt, 1)] = a; atomicAdd(&hist[(a >> 10) & 1023u], 1u); }
            a = v[i].z & 0x7FFFFFFFu; if ((a >> 20) == b0) { cand[atomicAdd(&s_cnt, 1)] = a; atomicAdd(&hist[(a >> 10) & 1023u], 1u); }
            a = v[i].w & 0x7FFFFFFFu; if ((a >> 20) == b0) { cand[atomicAdd(&s_cnt, 1)] = a; atomicAdd(&hist[(a >> 10) & 1023u], 1u); }
        }
        __syncthreads();
        select_bin<1024>(hist, s_part, &s_bin, &s_kk, &s_ceq, kk, tid);
        const uint32_t b1 = s_bin;
        kk = s_kk;
        hist[tid] = 0; hist[tid + 512] = 0;
        __syncthreads();
        for (int t = tid; t < ceq0; t += NT) {
            uint32_t a = cand[t];
            if (((a >> 10) & 1023u) == b1) atomicAdd(&hist[a & 1023u], 1u);
        }
        __syncthreads();
        select_bin<1024>(hist, s_part, &s_bin, &s_kk, &s_ceq, kk, tid);
        T = (b0 << 20) | (b1 << 10) | s_bin;
        e = s_kk; ceqT = s_ceq;
    } else {
        // ---- fallback (pathological skew): full-data rounds from registers ----
        #pragma unroll
        for (int i = 0; i < VPT; ++i) {
            uint32_t a;
            a = v[i].x & 0x7FFFFFFFu; if ((a >> 20) == b0) atomicAdd(&hist[(a >> 10) & 1023u], 1u);
            a = v[i].y & 0x7FFFFFFFu; if ((a >> 20) == b0) atomicAdd(&hist[(a >> 10) & 1023u], 1u);
            a = v[i].z & 0x7FFFFFFFu; if ((a >> 20) == b0) atomicAdd(&hist[(a >> 10) & 1023u], 1u);
            a = v[i].w & 0x7FFFFFFFu; if ((a >> 20) == b0) atomicAdd(&hist[(a >> 10) & 1023u], 1u);
        }
        __syncthreads();
        select_bin<1024>(hist, s_part, &s_bin, &s_kk, &s_ceq, kk, tid);
        const uint32_t b1 = s_bin;
        kk = s_kk;
        hist[tid] = 0; hist[tid + 512] = 0;
        __syncthreads();
        const uint32_t pfx = (b0 << 10) | b1;
        #pragma unroll
        for (int i = 0; i < VPT; ++i) {
            uint32_t a;
            a = v[i].x & 0x7FFFFFFFu; if ((a >> 10) == pfx) atomicAdd(&hist[a & 1023u], 1u);
            a = v[i].y & 0x7FFFFFFFu; if ((a >> 10) == pfx) atomicAdd(&hist[a & 1023u], 1u);
            a = v[i].z & 0x7FFFFFFFu; if ((a >> 10) == pfx) atomicAdd(&hist[a & 1023u], 1u);
            a = v[i].w & 0x7FFFFFFFu; if ((a >> 10) == pfx) atomicAdd(&hist[a & 1023u], 1u);
        }
        __syncthreads();
        select_bin<1024>(hist, s_part, &s_bin, &s_kk, &s_ceq, kk, tid);
        T = (b0 << 20) | (b1 << 10) | s_bin;
        e = s_kk; ceqT = s_ceq;
    }

    // ---- tie at the cutoff (≈never on random data): lowest-index-first ----
    const bool rare = (ceqT != e);
    int nc = 0;
    if (rare) {
        if (tid == 0) s_cnt = 0;
        __syncthreads();
        #pragma unroll
        for (int i = 0; i < VPT; ++i) {
            uint32_t p4 = (uint32_t)(4 * (i * NT + tid));
            if ((v[i].x & 0x7FFFFFFFu) == T) { int q = atomicAdd(&s_cnt, 1); if (q < 1024) hist[q] = p4 + 0u; }
            if ((v[i].y & 0x7FFFFFFFu) == T) { int q = atomicAdd(&s_cnt, 1); if (q < 1024) hist[q] = p4 + 1u; }
            if ((v[i].z & 0x7FFFFFFFu) == T) { int q = atomicAdd(&s_cnt, 1); if (q < 1024) hist[q] = p4 + 2u; }
            if ((v[i].w & 0x7FFFFFFFu) == T) { int q = atomicAdd(&s_cnt, 1); if (q < 1024) hist[q] = p4 + 3u; }
        }
        __syncthreads();
        nc = s_cnt; if (nc > 1024) nc = 1024;
        for (int t = tid; t < nc; t += NT) {
            uint32_t my = hist[t];
            int rank = 0;
            for (int j = 0; j < nc; ++j) rank += (hist[j] < my) ? 1 : 0;
            hist[1024 + t] = (rank < e) ? 1u : 0u;
        }
        __syncthreads();
    }

    // ---- Phase C: registers -> HBM, nontemporal (output never re-read;
    // avoids write-allocate evicting the input from L3 between replays) ----
    auto filt = [&](uint32_t bits, uint32_t idx) -> uint32_t {
        uint32_t key = bits & 0x7FFFFFFFu;
        if (key > T) return bits;
        if (key < T) return 0u;
        if (!rare) return bits;
        for (int j = 0; j < nc; ++j)
            if (hist[j] == idx) return hist[1024 + j] ? bits : 0u;
        return 0u;
    };
    #pragma unroll
    for (int i = 0; i < VPT; ++i) {
        int p = i * NT + tid;
        uint32_t p4 = (uint32_t)(4 * p);
        uint32x4 o;
        o.x = filt(v[i].x, p4 + 0u);
        o.y = filt(v[i].y, p4 + 1u);
        o.z = filt(v[i].z, p4 + 2u);
        o.w = filt(v[i].w, p4 + 3u);
        __builtin_nontemporal_store(o, &outr[p]);
    }
}

extern "C" void kernel_launch(void* const* d_in, const int* in_sizes, int n_in,
                              void* d_out, int out_size, void* d_ws, size_t ws_size,
                              hipStream_t stream) {
    const uint32_t* x = (const uint32_t*)d_in[0];
    const int* kptr   = (const int*)d_in[1];
    uint32_t* out     = (uint32_t*)d_out;
    const int rows = in_sizes[0] / ROWLEN;   // 4096 rows of 16384
    topk_abs_kernel<<<rows, NT, 0, stream>>>(x, kptr, out);
}